// Round 6
// baseline (263.597 us; speedup 1.0000x reference)
//
#include <hip/hip_runtime.h>
#include <hip/hip_bf16.h>
#include <stdint.h>

// Problem: B=2, S=2048, D=1024, H=16, DK=64.  M = B*S = 4096.
// Dtype detected at runtime (fp32 vs bf16), canonicalized to bf16.

typedef __attribute__((ext_vector_type(4))) float  f32x4;
typedef __attribute__((ext_vector_type(4))) int    i32x4;
typedef __attribute__((ext_vector_type(8))) __bf16 bf16x8;
typedef __attribute__((ext_vector_type(4))) __bf16 bf16x4;
typedef __attribute__((ext_vector_type(2))) __bf16 bf16x2;

#define MFMA16(a, b, c) __builtin_amdgcn_mfma_f32_16x16x32_bf16((a), (b), (c), 0, 0, 0)

__device__ __forceinline__ void async16(const void* g, void* lds) {
  __builtin_amdgcn_global_load_lds(
      (const __attribute__((address_space(1))) uint32_t*)g,
      (__attribute__((address_space(3))) uint32_t*)lds,
      16, 0, 0);
}

// XOR-swizzled LDS tile (row-major, 64 bf16 cols = 8 chunks of 16B): element
// (row, col/8) stored at chunk row*8 + ((col/8) ^ (row&7)).  ~2-way (free).
__device__ __forceinline__ bf16x8 lds_swz_read(const __bf16* base, int row, int cchunk) {
  const int sw = cchunk ^ (row & 7);
  return *(const bf16x8*)((const char*)base + row * 128 + sw * 16);
}

// ---- dtype detector: read w_q as bf16; fp32 mantissa low-halves decode huge.
__global__ void detect_dtype(const uint16_t* __restrict__ w, int* __restrict__ flag) {
  __shared__ int s;
  if (threadIdx.x == 0) s = 0;
  __syncthreads();
  int big = 0;
  for (int i = threadIdx.x; i < 8192; i += 256) {
    uint32_t u = ((uint32_t)w[i]) << 16;
    float f;
    __builtin_memcpy(&f, &u, 4);
    if (fabsf(f) > 1.0f) big = 1;   // xavier bound is 0.054
  }
  if (big) atomicOr(&s, 1);
  __syncthreads();
  if (threadIdx.x == 0) *flag = s;  // 1 = fp32 inputs, 0 = bf16 inputs
}

// ---- canonicalize all float tensors to bf16
struct CvtArgs { const void* src[8]; void* dst[8]; int n[8]; };

__global__ __launch_bounds__(256)
void convert_all(CvtArgs a, const int* __restrict__ flagp) {
  const int t = blockIdx.y;
  const int n = a.n[t];
  const int i0 = (blockIdx.x * 256 + threadIdx.x) * 8;
  if (i0 >= n) return;
  const int f = *flagp;
  if (f) {
    const float* s = (const float*)a.src[t];
    __bf16* d = (__bf16*)a.dst[t];
    bf16x8 v;
#pragma unroll
    for (int j = 0; j < 8; ++j) v[j] = (__bf16)s[i0 + j];
    *(bf16x8*)(d + i0) = v;
  } else {
    const i32x4* s = (const i32x4*)((const char*)a.src[t] + (size_t)i0 * 2);
    i32x4* d = (i32x4*)((char*)a.dst[t] + (size_t)i0 * 2);
    *d = *s;
  }
}

// C = A[4096,1024] @ W[1024,1024]^T  (NT, both K-contiguous, bf16).
// m97-style 128x128 tile, BK=32.  mode 0: QKV layout store; mode 1: bias + flat.
struct GemmArgs {
  const __bf16* A[3]; const __bf16* W[3]; void* C[3]; float scale[3];
  const __bf16* bias; const int* flagp; int mode;
};

__global__ __launch_bounds__(256, 2)
void gemm_nt(GemmArgs ga)
{
  constexpr int K = 1024;
  __shared__ __align__(16) __bf16 As[128 * 32];
  __shared__ __align__(16) __bf16 Bs[128 * 32];

  const int z = blockIdx.z;
  const __bf16* __restrict__ A = ga.A[z];
  const __bf16* __restrict__ W = ga.W[z];
  void* __restrict__ C = ga.C[z];
  const float scale = ga.scale[z];
  const int mode = ga.mode;

  const int tid = threadIdx.x;
  const int lane = tid & 63;
  const int wave = tid >> 6;
  const int l15 = lane & 15;
  const int quad = lane >> 4;
  const int bm = blockIdx.y * 128;
  const int bn = blockIdx.x * 128;
  const int wm = (wave >> 1) * 64;
  const int wn = (wave & 1) * 64;

  f32x4 acc[4][4];
#pragma unroll
  for (int mi = 0; mi < 4; ++mi)
#pragma unroll
    for (int ni = 0; ni < 4; ++ni) {
      f32x4 zz = {0.f, 0.f, 0.f, 0.f};
      acc[mi][ni] = zz;
    }

  for (int kt = 0; kt < K / 32; ++kt) {
    const int k0 = kt * 32;
    __syncthreads();
#pragma unroll
    for (int r = 0; r < 2; ++r) {
      const int chunk = r * 256 + wave * 64 + lane;
      const int row = chunk >> 2, c = chunk & 3;
      async16(A + (size_t)(bm + row) * K + k0 + c * 8, As + (r * 256 + wave * 64) * 8);
      async16(W + (size_t)(bn + row) * K + k0 + c * 8, Bs + (r * 256 + wave * 64) * 8);
    }
    __syncthreads();

    bf16x8 af[4];
    bf16x8 bfr[4];
#pragma unroll
    for (int mi = 0; mi < 4; ++mi)
      af[mi] = *(const bf16x8*)(As + (wm + mi * 16 + l15) * 32 + quad * 8);
#pragma unroll
    for (int ni = 0; ni < 4; ++ni)
      bfr[ni] = *(const bf16x8*)(Bs + (wn + ni * 16 + l15) * 32 + quad * 8);
#pragma unroll
    for (int mi = 0; mi < 4; ++mi)
#pragma unroll
      for (int ni = 0; ni < 4; ++ni)
        acc[mi][ni] = MFMA16(af[mi], bfr[ni], acc[mi][ni]);
  }

  const int f = (mode == 1) ? *ga.flagp : 0;
#pragma unroll
  for (int ni = 0; ni < 4; ++ni) {
    const int n = bn + wn + ni * 16 + l15;
    const float bv = (mode == 1) ? (float)ga.bias[n] : 0.0f;
#pragma unroll
    for (int mi = 0; mi < 4; ++mi) {
#pragma unroll
      for (int r = 0; r < 4; ++r) {
        const int m = bm + wm + mi * 16 + quad * 4 + r;
        const float v = acc[mi][ni][r] * scale + bv;
        if (mode == 0) {
          const int b = m >> 11, s = m & 2047, h = n >> 6, dk = n & 63;
          ((__bf16*)C)[((size_t)(b * 16 + h) * 2048 + s) * 64 + dk] = (__bf16)v;
        } else if (f) {
          ((float*)C)[(size_t)m * 1024 + n] = v;
        } else {
          ((__bf16*)C)[(size_t)m * 1024 + n] = (__bf16)v;
        }
      }
    }
  }
}

// Flash attention, S^T formulation, q-tile 128, K/V double-buffered with
// top-of-iter prefetch -> ONE barrier per iter, global latency off-chain.
// Q pre-scaled by 1/8.  Q/K/V layout [B*H][2048][64] bf16.
// S^T = K·Q^T (A=K, B=Q): C col=l15=q-in-strip, row=quad*4+r=k.
// O^T = V^T·P.  Two 64-row q-strips per block; V frags shared across strips.
__global__ __launch_bounds__(256, 2)
void attn(const __bf16* __restrict__ Q,
          const __bf16* __restrict__ Kg,
          const __bf16* __restrict__ Vg,
          __bf16* __restrict__ O)
{
  __shared__ __align__(16) __bf16 PsT[4][2][16][72];  // 18432 B; overlays Q staging
  __shared__ __align__(16) __bf16 Ks[2][64 * 64];     // swizzled K, dbuf (16 KB)
  __shared__ __align__(16) __bf16 Vts[2][64][72];     // V^T dbuf; reused as Ot[128][72]

  const int tid = threadIdx.x;
  const int lane = tid & 63;
  const int wave = tid >> 6;
  const int l15 = lane & 15;
  const int quad = lane >> 4;
  const int kp = tid & 31;     // V-transpose k-pair
  const int dg = tid >> 5;     // V-transpose d-group

  // balanced causal mapping: CU's 2 resident blocks (t, 15-t) sum to 34 iters
  int zb = blockIdx.x, t, bh;
  if (zb < 256) { t = zb & 15; bh = zb >> 4; }
  else { int z2 = zb - 256; t = 15 - (z2 & 15); bh = 16 + (z2 >> 4); }
  const int q0 = t * 128;
  const int nIter = 2 * t + 2;

  const __bf16* Qp = Q + (size_t)bh * 2048 * 64;
  const __bf16* Kp = Kg + (size_t)bh * 2048 * 64;
  const __bf16* Vp = Vg + (size_t)bh * 2048 * 64;

  __bf16* Qs = &PsT[0][0][0][0];   // 128x64 swizzled staging (16384 <= 18432)

  // ---- prologue: stage Q (async), K0 (async), V0 (regs) ----
#pragma unroll
  for (int r = 0; r < 4; ++r) {
    const int chunk = r * 256 + tid;
    const int row = chunk >> 3, c = (chunk & 7) ^ (row & 7);
    async16(Qp + (size_t)(q0 + row) * 64 + c * 8, (char*)Qs + (r * 256 + wave * 64) * 16);
  }
#pragma unroll
  for (int r = 0; r < 2; ++r) {
    const int chunk = r * 256 + tid;
    const int row = chunk >> 3, c = (chunk & 7) ^ (row & 7);
    async16(Kp + (size_t)row * 64 + c * 8, (char*)&Ks[0][0] + (r * 256 + wave * 64) * 16);
  }
  bf16x8 w0 = *(const bf16x8*)(Vp + (size_t)(2 * kp) * 64 + dg * 8);
  bf16x8 w1 = *(const bf16x8*)(Vp + (size_t)(2 * kp + 1) * 64 + dg * 8);

  __syncthreads();   // Q + K0 in LDS

#pragma unroll
  for (int j = 0; j < 8; ++j) {
    bf16x2 pr = { w0[j], w1[j] };
    *(bf16x2*)(&Vts[0][dg * 8 + j][2 * kp]) = pr;
  }
  const int qrow_wl = wave * 16 + l15;
  bf16x8 qf[2][2];
#pragma unroll
  for (int s = 0; s < 2; ++s)
#pragma unroll
    for (int kc = 0; kc < 2; ++kc)
      qf[s][kc] = lds_swz_read(Qs, s * 64 + qrow_wl, kc * 4 + quad);

  __syncthreads();   // V0 visible; Qs region free -> PsT

  f32x4 o_[2][4];
#pragma unroll
  for (int s = 0; s < 2; ++s)
#pragma unroll
    for (int dt = 0; dt < 4; ++dt) {
      f32x4 zz = {0.f, 0.f, 0.f, 0.f};
      o_[s][dt] = zz;
    }
  float mrow[2] = { -1e30f, -1e30f }, lrow[2] = { 0.0f, 0.0f };

  for (int kt = 0; kt < nIter; ++kt) {
    const int p = kt & 1;
    const bool pf_on = (kt + 1 < nIter);
    // ---- prefetch tile kt+1 into buffer p^1 (issued ~1000 cyc before drain)
    if (pf_on) {
      const int kn = (kt + 1) * 64;
#pragma unroll
      for (int r = 0; r < 2; ++r) {
        const int chunk = r * 256 + tid;
        const int row = chunk >> 3, c = (chunk & 7) ^ (row & 7);
        async16(Kp + (size_t)(kn + row) * 64 + c * 8,
                (char*)&Ks[p ^ 1][0] + (r * 256 + wave * 64) * 16);
      }
      w0 = *(const bf16x8*)(Vp + (size_t)(kn + 2 * kp) * 64 + dg * 8);
      w1 = *(const bf16x8*)(Vp + (size_t)(kn + 2 * kp + 1) * 64 + dg * 8);
    }

    // ---- S^T = K·Q^T, both strips (K frags shared)
    f32x4 st[2][4];
#pragma unroll
    for (int s = 0; s < 2; ++s)
#pragma unroll
      for (int nt = 0; nt < 4; ++nt) {
        f32x4 zz = {0.f, 0.f, 0.f, 0.f};
        st[s][nt] = zz;
      }
#pragma unroll
    for (int kc = 0; kc < 2; ++kc)
#pragma unroll
      for (int nt = 0; nt < 4; ++nt) {
        bf16x8 kf = lds_swz_read(&Ks[p][0], nt * 16 + l15, kc * 4 + quad);
        st[0][nt] = MFMA16(kf, qf[0][kc], st[0][nt]);
        st[1][nt] = MFMA16(kf, qf[1][kc], st[1][nt]);
      }

    // ---- causal mask (covers both diagonals + strip-0 overshoot tile)
    if (kt >= 2 * t) {
#pragma unroll
      for (int s = 0; s < 2; ++s)
#pragma unroll
        for (int nt = 0; nt < 4; ++nt)
#pragma unroll
          for (int r = 0; r < 4; ++r)
            if (64 * kt + nt * 16 + quad * 4 + r > 128 * t + s * 64 + qrow_wl)
              st[s][nt][r] = -1e30f;
    }

    // ---- online softmax per strip (per-lane scalar stats, 2 shfls each)
    float alpha[2];
#pragma unroll
    for (int s = 0; s < 2; ++s) {
      float tmax = -1e30f;
#pragma unroll
      for (int nt = 0; nt < 4; ++nt)
#pragma unroll
        for (int r = 0; r < 4; ++r) tmax = fmaxf(tmax, st[s][nt][r]);
      tmax = fmaxf(tmax, __shfl_xor(tmax, 16, 64));
      tmax = fmaxf(tmax, __shfl_xor(tmax, 32, 64));
      const float mnew = fmaxf(mrow[s], tmax);
      alpha[s] = __expf(mrow[s] - mnew);
      float rs = 0.0f;
#pragma unroll
      for (int nt = 0; nt < 4; ++nt) {
        bf16x4 pd;
#pragma unroll
        for (int r = 0; r < 4; ++r) {
          const float pv = __expf(st[s][nt][r] - mnew);
          rs += pv;
          pd[r] = (__bf16)pv;
        }
        *(bf16x4*)(&PsT[wave][s][l15][nt * 16 + quad * 4]) = pd;
      }
      rs += __shfl_xor(rs, 16, 64);
      rs += __shfl_xor(rs, 32, 64);
      lrow[s] = lrow[s] * alpha[s] + rs;
      mrow[s] = mnew;
    }
#pragma unroll
    for (int s = 0; s < 2; ++s)
#pragma unroll
      for (int dt = 0; dt < 4; ++dt) o_[s][dt] *= alpha[s];

    // ---- O^T += V^T · P  (V frags shared across strips)
#pragma unroll
    for (int kc = 0; kc < 2; ++kc) {
      bf16x8 pf0 = *(const bf16x8*)(&PsT[wave][0][l15][kc * 32 + quad * 8]);
      bf16x8 pf1 = *(const bf16x8*)(&PsT[wave][1][l15][kc * 32 + quad * 8]);
#pragma unroll
      for (int dt = 0; dt < 4; ++dt) {
        bf16x8 vf = *(const bf16x8*)(&Vts[p][dt * 16 + l15][kc * 32 + quad * 8]);
        o_[0][dt] = MFMA16(vf, pf0, o_[0][dt]);
        o_[1][dt] = MFMA16(vf, pf1, o_[1][dt]);
      }
    }

    // ---- store prefetched V^T into buffer p^1 (read last in iter kt-1)
    if (pf_on) {
#pragma unroll
      for (int j = 0; j < 8; ++j) {
        bf16x2 pr = { w0[j], w1[j] };
        *(bf16x2*)(&Vts[p ^ 1][dg * 8 + j][2 * kp]) = pr;
      }
    }
    __syncthreads();  // drains prefetch (aged ~full iter) + publishes buffers
  }

  // ---- epilogue: normalize, transpose via LDS (reuse Vts as Ot[128][72])
  __bf16 (*Ot)[72] = (__bf16(*)[72])&Vts[0][0][0];
#pragma unroll
  for (int s = 0; s < 2; ++s) {
    const float inv_l = 1.0f / lrow[s];
#pragma unroll
    for (int dt = 0; dt < 4; ++dt)
#pragma unroll
      for (int r = 0; r < 4; r += 2) {
        bf16x2 pr = { (__bf16)(o_[s][dt][r] * inv_l),
                      (__bf16)(o_[s][dt][r + 1] * inv_l) };
        *(bf16x2*)(&Ot[s * 64 + qrow_wl][dt * 16 + quad * 4 + r]) = pr;
      }
  }
  __syncthreads();

  const int b = bh >> 4, h = bh & 15;
#pragma unroll
  for (int r = 0; r < 4; ++r) {
    const int i = r * 256 + tid;
    const int row = i >> 3, c = i & 7;
    f32x4 v = *(const f32x4*)(&Ot[row][c * 8]);
    *(f32x4*)(O + (size_t)(b * 2048 + q0 + row) * 1024 + h * 64 + c * 8) = v;
  }
}

extern "C" void kernel_launch(void* const* d_in, const int* in_sizes, int n_in,
                              void* d_out, int out_size, void* d_ws, size_t ws_size,
                              hipStream_t stream) {
  char* ws = (char*)d_ws;
  int* flag = (int*)ws;
  __bf16* Xc0 = (__bf16*)(ws + (1u << 20));    // 8 MB each
  __bf16* Xc1 = (__bf16*)(ws + (9u << 20));
  __bf16* Xc2 = (__bf16*)(ws + (17u << 20));
  __bf16* Wc0 = (__bf16*)(ws + (25u << 20));   // 2 MB each
  __bf16* Wc1 = (__bf16*)(ws + (27u << 20));
  __bf16* Wc2 = (__bf16*)(ws + (29u << 20));
  __bf16* Wc3 = (__bf16*)(ws + (31u << 20));
  __bf16* bc  = (__bf16*)(ws + (33u << 20));
  __bf16* Qw  = (__bf16*)(ws + (34u << 20));   // 8 MB each, [B*H][S][64]
  __bf16* Kw  = (__bf16*)(ws + (42u << 20));
  __bf16* Vw  = (__bf16*)(ws + (50u << 20));
  __bf16* Aw  = Xc0;                           // X dead after projections

  detect_dtype<<<1, 256, 0, stream>>>((const uint16_t*)d_in[4], flag);

  CvtArgs ca;
  ca.src[0] = d_in[0]; ca.dst[0] = Xc0; ca.n[0] = 4194304;
  ca.src[1] = d_in[1]; ca.dst[1] = Xc1; ca.n[1] = 4194304;
  ca.src[2] = d_in[2]; ca.dst[2] = Xc2; ca.n[2] = 4194304;
  ca.src[3] = d_in[4]; ca.dst[3] = Wc0; ca.n[3] = 1048576;
  ca.src[4] = d_in[5]; ca.dst[4] = Wc1; ca.n[4] = 1048576;
  ca.src[5] = d_in[6]; ca.dst[5] = Wc2; ca.n[5] = 1048576;
  ca.src[6] = d_in[7]; ca.dst[6] = Wc3; ca.n[6] = 1048576;
  ca.src[7] = d_in[8]; ca.dst[7] = bc;  ca.n[7] = 1024;
  convert_all<<<dim3(2048, 8), 256, 0, stream>>>(ca, flag);

  // fused Q/K/V projections (scores scale 1/8 folded into Q)
  GemmArgs g0;
  g0.A[0] = Xc0; g0.W[0] = Wc0; g0.C[0] = Qw; g0.scale[0] = 0.125f;
  g0.A[1] = Xc1; g0.W[1] = Wc1; g0.C[1] = Kw; g0.scale[1] = 1.0f;
  g0.A[2] = Xc2; g0.W[2] = Wc2; g0.C[2] = Vw; g0.scale[2] = 1.0f;
  g0.bias = nullptr; g0.flagp = flag; g0.mode = 0;
  gemm_nt<<<dim3(8, 32, 3), 256, 0, stream>>>(g0);

  attn<<<dim3(512), 256, 0, stream>>>(Qw, Kw, Vw, Aw);

  GemmArgs g1;
  g1.A[0] = Aw; g1.W[0] = Wc3; g1.C[0] = d_out; g1.scale[0] = 1.0f;
  g1.A[1] = nullptr; g1.W[1] = nullptr; g1.C[1] = nullptr; g1.scale[1] = 0.f;
  g1.A[2] = nullptr; g1.W[2] = nullptr; g1.C[2] = nullptr; g1.scale[2] = 0.f;
  g1.bias = bc; g1.flagp = flag; g1.mode = 1;
  gemm_nt<<<dim3(8, 32, 1), 256, 0, stream>>>(g1);
}